// Round 9
// baseline (493.923 us; speedup 1.0000x reference)
//
#include <hip/hip_runtime.h>

#define NN 100000
#define NB ((NN + 255) / 256)   // 391 scan blocks
#define NT 1563                  // 64-row GEMM tiles
#define SPLIT 782                // tiles handled by fusedA

// bf16 helpers (RNE pack)
__device__ __forceinline__ unsigned short f2bf(float x) {
    unsigned u = __float_as_uint(x);
    u += 0x7fff + ((u >> 16) & 1);
    return (unsigned short)(u >> 16);
}
__device__ __forceinline__ float bf2f(unsigned short h) {
    return __uint_as_float(((unsigned)h) << 16);
}

// ======== dual GEMM tile: rows [rb*64,+64), y1(bf16,64c) = x@W1l.T, h(fp32,64c) = x@W1r.T
// 256 thr: cg=tid&15 (4 cols), rq=tid>>4 (4 rows rq*4+i). K tiled at 64.
// LDS 52.2KB -> 3 blocks/CU.
__device__ __forceinline__ void gemm_dual(const float* __restrict__ x,
        const float* __restrict__ Wl, const float* __restrict__ Wr,
        unsigned short* __restrict__ y1, float* __restrict__ h,
        int rb, int tid, float (*lx)[68], float (*lwl)[68], float (*lwr)[68]) {
    const int row0 = rb * 64;
    const int cg = tid & 15, rq = tid >> 4;
    float accL[4][4] = {{0.f}}, accR[4][4] = {{0.f}};
    for (int kt = 0; kt < 2; ++kt) {
        if (kt) __syncthreads();
        #pragma unroll
        for (int i = 0; i < 4; ++i) {          // lx: 1024 float4 (64 rows x 16)
            int idx = i * 256 + tid;
            int r = idx >> 4, k4 = (idx & 15) << 2;
            int grow = row0 + r;
            float4 v = make_float4(0.f, 0.f, 0.f, 0.f);
            if (grow < NN) v = *(const float4*)(x + (size_t)grow * 128 + kt * 64 + k4);
            *(float4*)(&lx[r][k4]) = v;
        }
        #pragma unroll
        for (int i = 0; i < 4; ++i) {          // lw[k][j]: strided global, clean LDS write
            int idx = i * 256 + tid;
            int j = idx & 63, k4 = (idx >> 6) << 2;
            float4 a = *(const float4*)(Wl + (size_t)j * 128 + kt * 64 + k4);
            lwl[k4 + 0][j] = a.x; lwl[k4 + 1][j] = a.y;
            lwl[k4 + 2][j] = a.z; lwl[k4 + 3][j] = a.w;
            float4 b = *(const float4*)(Wr + (size_t)j * 128 + kt * 64 + k4);
            lwr[k4 + 0][j] = b.x; lwr[k4 + 1][j] = b.y;
            lwr[k4 + 2][j] = b.z; lwr[k4 + 3][j] = b.w;
        }
        __syncthreads();
        #pragma unroll 4
        for (int k = 0; k < 64; ++k) {
            float4 wl = *(const float4*)(&lwl[k][cg << 2]);
            float4 wr = *(const float4*)(&lwr[k][cg << 2]);
            #pragma unroll
            for (int i = 0; i < 4; ++i) {
                float xv = lx[rq * 4 + i][k];
                accL[i][0] = fmaf(xv, wl.x, accL[i][0]);
                accL[i][1] = fmaf(xv, wl.y, accL[i][1]);
                accL[i][2] = fmaf(xv, wl.z, accL[i][2]);
                accL[i][3] = fmaf(xv, wl.w, accL[i][3]);
                accR[i][0] = fmaf(xv, wr.x, accR[i][0]);
                accR[i][1] = fmaf(xv, wr.y, accR[i][1]);
                accR[i][2] = fmaf(xv, wr.z, accR[i][2]);
                accR[i][3] = fmaf(xv, wr.w, accR[i][3]);
            }
        }
    }
    #pragma unroll
    for (int i = 0; i < 4; ++i) {
        int grow = row0 + rq * 4 + i;
        if (grow < NN) {
            ushort4 o;
            o.x = f2bf(accL[i][0]); o.y = f2bf(accL[i][1]);
            o.z = f2bf(accL[i][2]); o.w = f2bf(accL[i][3]);
            *(ushort4*)(y1 + (size_t)grow * 64 + (cg << 2)) = o;
            *(float4*)(h + (size_t)grow * 64 + (cg << 2)) =
                make_float4(accR[i][0], accR[i][1], accR[i][2], accR[i][3]);
        }
    }
}

// ======== fusedA: deg histogram + dual-GEMM tiles [0,SPLIT) ====================
// grid 1568 = 98 groups x 16: v<8 deg role (2048 edges), v>=8 gemm role.
__global__ __launch_bounds__(256) void k_fusedA(const float* __restrict__ x,
        const float* __restrict__ W1l, const float* __restrict__ W1r,
        const int* __restrict__ dst, int* __restrict__ deg,
        unsigned short* __restrict__ y1, float* __restrict__ h, int E) {
    __shared__ float lx[64][68];
    __shared__ float lwl[64][68];
    __shared__ float lwr[64][68];
    const int tid = threadIdx.x;
    const int u = blockIdx.x >> 4, v = blockIdx.x & 15;
    if (v < 8) {
        const int base = (u * 8 + v) * 2048;
        #pragma unroll
        for (int i = 0; i < 8; ++i) {
            int e = base + i * 256 + tid;
            if (e < E) atomicAdd(&deg[dst[e]], 1);
        }
        return;
    }
    const int rb = u * 8 + (v - 8);
    if (rb >= SPLIT) return;
    gemm_dual(x, W1l, W1r, y1, h, rb, tid, lx, lwl, lwr);
}

// ======== fusedB: XCD-seg CSR fill + dual-GEMM tiles [SPLIT,NT) ================
// fill role: block (u, s=v) scans edges [u*16384,+16384) keeping dst in
// [s*12500,+12500) -> eidx writes land in one XCD-owned region.
__global__ __launch_bounds__(256) void k_fusedB(const float* __restrict__ x,
        const float* __restrict__ W1l, const float* __restrict__ W1r,
        const int* __restrict__ src, const int* __restrict__ dst,
        int* __restrict__ cursor, int* __restrict__ eidx,
        unsigned short* __restrict__ y1, float* __restrict__ h, int E) {
    __shared__ float lx[64][68];
    __shared__ float lwl[64][68];
    __shared__ float lwr[64][68];
    const int tid = threadIdx.x;
    const int u = blockIdx.x >> 4, v = blockIdx.x & 15;
    if (v < 8) {
        const int base = u * 16384;
        const int lo = v * 12500, hi = lo + 12500;
        #pragma unroll 4
        for (int i = 0; i < 64; ++i) {
            int e = base + i * 256 + tid;
            if (e < E) {
                int d = dst[e];
                if (d >= lo && d < hi) {
                    int pos = atomicAdd(&cursor[d], 1);
                    eidx[pos] = src[e];
                }
            }
        }
        return;
    }
    const int rb = SPLIT + u * 8 + (v - 8);
    if (rb >= NT) return;
    gemm_dual(x, W1l, W1r, y1, h, rb, tid, lx, lwl, lwr);
}

// ---------------- scan pass A ----------------------------------------------------
__global__ __launch_bounds__(256) void k_scanA(const int* __restrict__ deg,
                                               int* __restrict__ rowptr,
                                               int* __restrict__ bsum) {
    const int tid = threadIdx.x;
    const int i = blockIdx.x * 256 + tid;
    int v = (i < NN) ? deg[i] : 0;
    const int lane = tid & 63, w = tid >> 6;
    int inc = v;
    #pragma unroll
    for (int d = 1; d < 64; d <<= 1) {
        int t = __shfl_up(inc, d, 64);
        if (lane >= d) inc += t;
    }
    __shared__ int wsum[4];
    if (lane == 63) wsum[w] = inc;
    __syncthreads();
    int wo = 0;
    for (int k = 0; k < w; ++k) wo += wsum[k];
    if (i < NN) rowptr[i] = wo + inc - v;
    if (tid == 255) bsum[blockIdx.x] = wo + inc;
}

// ---------------- scan pass B ----------------------------------------------------
__global__ __launch_bounds__(512) void k_scanB(int* __restrict__ bsum,
                                               int* __restrict__ rowptr, int E) {
    const int tid = threadIdx.x;
    int v = (tid < NB) ? bsum[tid] : 0;
    const int lane = tid & 63, w = tid >> 6;
    int inc = v;
    #pragma unroll
    for (int d = 1; d < 64; d <<= 1) {
        int t = __shfl_up(inc, d, 64);
        if (lane >= d) inc += t;
    }
    __shared__ int wsum[8];
    if (lane == 63) wsum[w] = inc;
    __syncthreads();
    int wo = 0;
    for (int k = 0; k < w; ++k) wo += wsum[k];
    if (tid < NB) bsum[tid] = wo + inc - v;
    if (tid == 0) rowptr[NN] = E;
}

// ---------------- finish ---------------------------------------------------------
__global__ void k_finish(int* __restrict__ rowptr, const int* __restrict__ bsum,
                         const int* __restrict__ deg, int* __restrict__ cursor,
                         float* __restrict__ deg_inv) {
    int i = blockIdx.x * 256 + threadIdx.x;
    if (i < NN) {
        int rp = rowptr[i] + bsum[i >> 8];
        rowptr[i] = rp;
        cursor[i] = rp;
        deg_inv[i] = 1.0f / fmaxf((float)deg[i], 1.0f);
    }
}

// ---------------- gather1: h = mean(bf16 y1[nbrs])*deg_inv + xr + b1l; BN stats --
__global__ __launch_bounds__(256) void k_gather1(const unsigned short* __restrict__ y1,
        const int* __restrict__ rowptr, const int* __restrict__ eidx,
        const float* __restrict__ b1l,
        const float* __restrict__ deg_inv, float* __restrict__ h,
        float* __restrict__ stats) {
    const int tid = threadIdx.x;
    const int f = tid & 63, w = tid >> 6;
    const float bias = b1l[f];
    float a1 = 0.f, a2 = 0.f;
    for (int n = blockIdx.x * 4 + w; n < NN; n += gridDim.x * 4) {
        int beg = rowptr[n], end = rowptr[n + 1];
        float s0 = 0.f, s1 = 0.f, s2 = 0.f, s3 = 0.f;
        int j = beg;
        for (; j + 3 < end; j += 4) {
            int i0 = eidx[j], i1 = eidx[j + 1], i2 = eidx[j + 2], i3 = eidx[j + 3];
            s0 += bf2f(y1[(size_t)i0 * 64 + f]);
            s1 += bf2f(y1[(size_t)i1 * 64 + f]);
            s2 += bf2f(y1[(size_t)i2 * 64 + f]);
            s3 += bf2f(y1[(size_t)i3 * 64 + f]);
        }
        for (; j < end; ++j) s0 += bf2f(y1[(size_t)eidx[j] * 64 + f]);
        size_t off = (size_t)n * 64 + f;
        float hv = fmaf((s0 + s1) + (s2 + s3), deg_inv[n], h[off] + bias); // h holds xr
        h[off] = hv;
        a1 += hv; a2 = fmaf(hv, hv, a2);
    }
    __shared__ float sA[4][64], sB[4][64];
    sA[w][f] = a1; sB[w][f] = a2;
    __syncthreads();
    if (w == 0) {
        atomicAdd(&stats[f],      sA[0][f] + sA[1][f] + sA[2][f] + sA[3][f]);
        atomicAdd(&stats[64 + f], sB[0][f] + sB[1][f] + sB[2][f] + sB[3][f]);
    }
}

// ---------------- GEMM2 (BN finalize + BN+ReLU fused): y2(bf16), hr2(fp32) -------
__global__ __launch_bounds__(256) void k_gemm2(const float* __restrict__ h,
        const float* __restrict__ W2l, const float* __restrict__ W2r,
        const float* __restrict__ stats, const float* __restrict__ gamma,
        const float* __restrict__ beta,
        unsigned short* __restrict__ y2, float* __restrict__ hr2) {
    __shared__ float lh[64][68];
    __shared__ float lw[64][36];
    __shared__ float lsc[64], lsh[64];
    const int tid = threadIdx.x;
    if (tid < 64) {   // BN finalize (redundant per block, cheap)
        float mu = stats[tid] * (1.0f / NN);
        float var = stats[64 + tid] * (1.0f / NN) - mu * mu;
        float sc = gamma[tid] * rsqrtf(var + 1e-5f);
        lsc[tid] = sc;
        lsh[tid] = beta[tid] - mu * sc;
    }
    for (int idx = tid; idx < 32 * 64; idx += 256) {
        int j = idx >> 6, k = idx & 63;
        lw[k][j] = (j < 16) ? W2l[idx] : W2r[idx - 1024];
    }
    __syncthreads();
    const int row0 = blockIdx.x * 64;
    for (int i = 0; i < 4; ++i) {
        int f4 = i * 256 + tid;
        int r = f4 >> 4;
        int k4 = (f4 & 15) << 2;
        int grow = row0 + r;
        float4 v = make_float4(0.f, 0.f, 0.f, 0.f);
        if (grow < NN) v = *(const float4*)(h + (size_t)grow * 64 + k4);
        float4 sc = *(const float4*)(&lsc[k4]);
        float4 sh = *(const float4*)(&lsh[k4]);
        float4 o;
        o.x = fmaxf(fmaf(v.x, sc.x, sh.x), 0.f);
        o.y = fmaxf(fmaf(v.y, sc.y, sh.y), 0.f);
        o.z = fmaxf(fmaf(v.z, sc.z, sh.z), 0.f);
        o.w = fmaxf(fmaf(v.w, sc.w, sh.w), 0.f);
        *(float4*)(&lh[r][k4]) = o;
    }
    __syncthreads();
    const int cg = tid & 7;
    const int rl = tid >> 3;
    #pragma unroll
    for (int p = 0; p < 2; ++p) {
        int r = p * 32 + rl;
        int grow = row0 + r;
        float ax = 0.f, ay = 0.f, az = 0.f, aw = 0.f;
        #pragma unroll
        for (int k = 0; k < 64; ++k) {
            float hv = lh[r][k];
            float4 wv = *(const float4*)(&lw[k][cg << 2]);
            ax = fmaf(hv, wv.x, ax); ay = fmaf(hv, wv.y, ay);
            az = fmaf(hv, wv.z, az); aw = fmaf(hv, wv.w, aw);
        }
        if (grow < NN) {
            int c = cg << 2;
            if (c < 16) {
                ushort4 o;
                o.x = f2bf(ax); o.y = f2bf(ay); o.z = f2bf(az); o.w = f2bf(aw);
                *(ushort4*)(y2 + (size_t)grow * 16 + c) = o;
            } else {
                *(float4*)(hr2 + (size_t)grow * 16 + (c - 16)) = make_float4(ax, ay, az, aw);
            }
        }
    }
}

// ---------------- gather2 + epilogue: emb + logits straight to d_out -------------
__global__ __launch_bounds__(256) void k_gather2(const unsigned short* __restrict__ y2,
        const int* __restrict__ rowptr, const int* __restrict__ eidx,
        const float* __restrict__ hr2, const float* __restrict__ b2l,
        const float* __restrict__ deg_inv, const float* __restrict__ Wc,
        const float* __restrict__ bc, float* __restrict__ out) {
    const int tid = threadIdx.x;
    const int f = tid & 15, g = tid >> 4;
    const float wc0 = Wc[f], wc1 = Wc[16 + f];
    const float bias = b2l[f];
    for (int n = blockIdx.x * 16 + g; n < NN; n += gridDim.x * 16) {
        int beg = rowptr[n], end = rowptr[n + 1];
        float s0 = 0.f, s1 = 0.f, s2 = 0.f, s3 = 0.f;
        int j = beg;
        for (; j + 3 < end; j += 4) {
            int i0 = eidx[j], i1 = eidx[j + 1], i2 = eidx[j + 2], i3 = eidx[j + 3];
            s0 += bf2f(y2[(size_t)i0 * 16 + f]);
            s1 += bf2f(y2[(size_t)i1 * 16 + f]);
            s2 += bf2f(y2[(size_t)i2 * 16 + f]);
            s3 += bf2f(y2[(size_t)i3 * 16 + f]);
        }
        for (; j < end; ++j) s0 += bf2f(y2[(size_t)eidx[j] * 16 + f]);
        float e = fmaf((s0 + s1) + (s2 + s3), deg_inv[n], hr2[(size_t)n * 16 + f] + bias);
        out[(size_t)(2 * NN) + (size_t)n * 16 + f] = e;
        float l0 = e * wc0, l1 = e * wc1;
        #pragma unroll
        for (int m = 1; m < 16; m <<= 1) {
            l0 += __shfl_xor(l0, m, 64);
            l1 += __shfl_xor(l1, m, 64);
        }
        if (f == 0) {
            out[(size_t)n * 2]     = l0 + bc[0];
            out[(size_t)n * 2 + 1] = l1 + bc[1];
        }
    }
}

extern "C" void kernel_launch(void* const* d_in, const int* in_sizes, int n_in,
                              void* d_out, int out_size, void* d_ws, size_t ws_size,
                              hipStream_t stream) {
    const float* x     = (const float*)d_in[0];
    const int*   src   = (const int*)d_in[1];
    const int*   dst   = (const int*)d_in[2];
    const float* W1l   = (const float*)d_in[3];
    const float* b1l   = (const float*)d_in[4];
    const float* W1r   = (const float*)d_in[5];
    const float* gamma = (const float*)d_in[6];
    const float* beta  = (const float*)d_in[7];
    const float* W2l   = (const float*)d_in[8];
    const float* b2l   = (const float*)d_in[9];
    const float* W2r   = (const float*)d_in[10];
    const float* Wc    = (const float*)d_in[11];
    const float* bc    = (const float*)d_in[12];
    const int E = in_sizes[1];

    // ---- workspace layout (floats) ----------------------------------------------
    // rowptr[100352] | deg_inv[100352] | stats[256] | deg_i[100352] | cursor[100352]
    // | eidx[E] | y1 region[NN*64 fl] (bf16 y1 uses half) | h[NN*64]
    // overlays: bsum in eidx region; y2(bf16)/hr2 reuse y1 region after gather1;
    //           xr IS h (fused gemm writes it, gather1 updates in place).
    float* ws      = (float*)d_ws;
    int*   rowptr  = (int*)ws;
    float* deg_inv = ws + 100352;
    float* stats   = ws + 200704;
    int*   deg_i   = (int*)(ws + 200960);
    int*   cursor  = (int*)(ws + 301312);
    int*   eidx    = (int*)(ws + 401664);
    float* y1reg   = ws + 401664 + (size_t)E;
    float* h       = y1reg + (size_t)NN * 64;
    unsigned short* y1 = (unsigned short*)y1reg;
    int*   bsum    = eidx;
    unsigned short* y2 = (unsigned short*)y1reg;
    float* hr2     = y1reg + (size_t)NN * 8;   // after y2's NN*16 ushorts
    float* out     = (float*)d_out;

    hipMemsetAsync(deg_i, 0, NN * sizeof(int), stream);
    hipMemsetAsync(stats, 0, 256 * sizeof(float), stream);

    // fusedA: deg + dual-GEMM tiles [0,782). 98 groups x 16 blocks.
    k_fusedA<<<1568, 256, 0, stream>>>(x, W1l, W1r, dst, deg_i, y1, h, E);

    k_scanA<<<NB, 256, 0, stream>>>(deg_i, rowptr, bsum);
    k_scanB<<<1, 512, 0, stream>>>(bsum, rowptr, E);
    k_finish<<<NB, 256, 0, stream>>>(rowptr, bsum, deg_i, cursor, deg_inv);

    // fusedB: XCD-seg fill + dual-GEMM tiles [782,1563).
    k_fusedB<<<1568, 256, 0, stream>>>(x, W1l, W1r, src, dst, cursor, eidx, y1, h, E);

    k_gather1<<<4096, 256, 0, stream>>>(y1, rowptr, eidx, b1l, deg_inv, h, stats);

    k_gemm2<<<(NN + 63) / 64, 256, 0, stream>>>(h, W2l, W2r, stats, gamma, beta, y2, hr2);

    k_gather2<<<2048, 256, 0, stream>>>(y2, rowptr, eidx, hr2, b2l, deg_inv, Wc, bc, out);
}

// Round 13
// 453.201 us; speedup vs baseline: 1.0899x; 1.0899x over previous
//
#include <hip/hip_runtime.h>

#define NN 100000
#define NB ((NN + 255) / 256)   // 391 scan blocks
#define NT 1563                  // 64-row GEMM tiles
#define SPLIT 782                // tiles handled by fusedA

// bf16 helpers (RNE pack)
__device__ __forceinline__ unsigned short f2bf(float x) {
    unsigned u = __float_as_uint(x);
    u += 0x7fff + ((u >> 16) & 1);
    return (unsigned short)(u >> 16);
}
__device__ __forceinline__ float bf2f(unsigned short h) {
    return __uint_as_float(((unsigned)h) << 16);
}

// ======== dual GEMM tile: rows [rb*64,+64), y1(bf16) = x@W1l.T, h(fp32) = x@W1r.T
// 256 thr: cg=tid&15 (4 cols), rq=tid>>4 (rows rq*4+i). K tiled at 32.
// LDS 26 KB -> ~6 blocks/CU (the round-9 52 KB variant collapsed occupancy).
__device__ __forceinline__ void gemm_dual(const float* __restrict__ x,
        const float* __restrict__ Wl, const float* __restrict__ Wr,
        unsigned short* __restrict__ y1, float* __restrict__ h,
        int rb, int tid, float (*lx)[36], float (*lwl)[68], float (*lwr)[68]) {
    const int row0 = rb * 64;
    const int cg = tid & 15, rq = tid >> 4;
    float accL[4][4] = {{0.f}}, accR[4][4] = {{0.f}};
    for (int kt = 0; kt < 4; ++kt) {
        if (kt) __syncthreads();
        #pragma unroll
        for (int i = 0; i < 2; ++i) {          // lx: 512 float4 (64 rows x 8)
            int idx = i * 256 + tid;
            int r = idx >> 3, k4 = (idx & 7) << 2;
            int grow = row0 + r;
            float4 v = make_float4(0.f, 0.f, 0.f, 0.f);
            if (grow < NN) v = *(const float4*)(x + (size_t)grow * 128 + kt * 32 + k4);
            *(float4*)(&lx[r][k4]) = v;
        }
        #pragma unroll
        for (int i = 0; i < 2; ++i) {          // lw[k][j]: strided global, clean LDS write
            int idx = i * 256 + tid;
            int j = idx & 63, k4 = (idx >> 6) << 2;   // k4 in {0,4,...,28}
            float4 a = *(const float4*)(Wl + (size_t)j * 128 + kt * 32 + k4);
            lwl[k4 + 0][j] = a.x; lwl[k4 + 1][j] = a.y;
            lwl[k4 + 2][j] = a.z; lwl[k4 + 3][j] = a.w;
            float4 b = *(const float4*)(Wr + (size_t)j * 128 + kt * 32 + k4);
            lwr[k4 + 0][j] = b.x; lwr[k4 + 1][j] = b.y;
            lwr[k4 + 2][j] = b.z; lwr[k4 + 3][j] = b.w;
        }
        __syncthreads();
        #pragma unroll 4
        for (int k = 0; k < 32; ++k) {
            float4 wl = *(const float4*)(&lwl[k][cg << 2]);
            float4 wr = *(const float4*)(&lwr[k][cg << 2]);
            #pragma unroll
            for (int i = 0; i < 4; ++i) {
                float xv = lx[rq * 4 + i][k];
                accL[i][0] = fmaf(xv, wl.x, accL[i][0]);
                accL[i][1] = fmaf(xv, wl.y, accL[i][1]);
                accL[i][2] = fmaf(xv, wl.z, accL[i][2]);
                accL[i][3] = fmaf(xv, wl.w, accL[i][3]);
                accR[i][0] = fmaf(xv, wr.x, accR[i][0]);
                accR[i][1] = fmaf(xv, wr.y, accR[i][1]);
                accR[i][2] = fmaf(xv, wr.z, accR[i][2]);
                accR[i][3] = fmaf(xv, wr.w, accR[i][3]);
            }
        }
    }
    #pragma unroll
    for (int i = 0; i < 4; ++i) {
        int grow = row0 + rq * 4 + i;
        if (grow < NN) {
            ushort4 o;
            o.x = f2bf(accL[i][0]); o.y = f2bf(accL[i][1]);
            o.z = f2bf(accL[i][2]); o.w = f2bf(accL[i][3]);
            *(ushort4*)(y1 + (size_t)grow * 64 + (cg << 2)) = o;
            *(float4*)(h + (size_t)grow * 64 + (cg << 2)) =
                make_float4(accR[i][0], accR[i][1], accR[i][2], accR[i][3]);
        }
    }
}

// ======== fusedA: deg histogram + dual-GEMM tiles [0,SPLIT) ====================
// grid 1568 = 98 groups x 16: v<8 deg role (2048 edges, 8 iters, exits fast),
// v>=8 gemm role.
__global__ __launch_bounds__(256) void k_fusedA(const float* __restrict__ x,
        const float* __restrict__ W1l, const float* __restrict__ W1r,
        const int* __restrict__ dst, int* __restrict__ deg,
        unsigned short* __restrict__ y1, float* __restrict__ h, int E) {
    __shared__ float lx[64][36];
    __shared__ float lwl[32][68];
    __shared__ float lwr[32][68];
    const int tid = threadIdx.x;
    const int u = blockIdx.x >> 4, v = blockIdx.x & 15;
    if (v < 8) {
        const int base = (u * 8 + v) * 2048;
        #pragma unroll
        for (int i = 0; i < 8; ++i) {
            int e = base + i * 256 + tid;
            if (e < E) atomicAdd(&deg[dst[e]], 1);
        }
        return;
    }
    const int rb = u * 8 + (v - 8);
    if (rb >= SPLIT) return;
    gemm_dual(x, W1l, W1r, y1, h, rb, tid, lx, lwl, lwr);
}

// ======== fusedB: plain CSR fill + dual-GEMM tiles [SPLIT,NT) ==================
// fill role: v<4, chunk c = u*4+v covers 4096 edges (16 iters) -> releases LDS
// fast. Unsegmented (round-9 counters showed segmentation didn't cut the
// false-sharing writes; this version drops the 8x dst-scan amplification).
__global__ __launch_bounds__(256) void k_fusedB(const float* __restrict__ x,
        const float* __restrict__ W1l, const float* __restrict__ W1r,
        const int* __restrict__ src, const int* __restrict__ dst,
        int* __restrict__ cursor, int* __restrict__ eidx,
        unsigned short* __restrict__ y1, float* __restrict__ h, int E) {
    __shared__ float lx[64][36];
    __shared__ float lwl[32][68];
    __shared__ float lwr[32][68];
    const int tid = threadIdx.x;
    const int u = blockIdx.x >> 4, v = blockIdx.x & 15;
    if (v < 4) {
        const int base = (u * 4 + v) * 4096;
        #pragma unroll 4
        for (int i = 0; i < 16; ++i) {
            int e = base + i * 256 + tid;
            if (e < E) {
                int d = dst[e];
                int pos = atomicAdd(&cursor[d], 1);
                eidx[pos] = src[e];
            }
        }
        return;
    }
    const int rb = SPLIT + u * 12 + (v - 4);
    if (rb >= NT) return;
    gemm_dual(x, W1l, W1r, y1, h, rb, tid, lx, lwl, lwr);
}

// ---------------- scan pass A ----------------------------------------------------
__global__ __launch_bounds__(256) void k_scanA(const int* __restrict__ deg,
                                               int* __restrict__ rowptr,
                                               int* __restrict__ bsum) {
    const int tid = threadIdx.x;
    const int i = blockIdx.x * 256 + tid;
    int v = (i < NN) ? deg[i] : 0;
    const int lane = tid & 63, w = tid >> 6;
    int inc = v;
    #pragma unroll
    for (int d = 1; d < 64; d <<= 1) {
        int t = __shfl_up(inc, d, 64);
        if (lane >= d) inc += t;
    }
    __shared__ int wsum[4];
    if (lane == 63) wsum[w] = inc;
    __syncthreads();
    int wo = 0;
    for (int k = 0; k < w; ++k) wo += wsum[k];
    if (i < NN) rowptr[i] = wo + inc - v;
    if (tid == 255) bsum[blockIdx.x] = wo + inc;
}

// ---------------- scan pass B ----------------------------------------------------
__global__ __launch_bounds__(512) void k_scanB(int* __restrict__ bsum,
                                               int* __restrict__ rowptr, int E) {
    const int tid = threadIdx.x;
    int v = (tid < NB) ? bsum[tid] : 0;
    const int lane = tid & 63, w = tid >> 6;
    int inc = v;
    #pragma unroll
    for (int d = 1; d < 64; d <<= 1) {
        int t = __shfl_up(inc, d, 64);
        if (lane >= d) inc += t;
    }
    __shared__ int wsum[8];
    if (lane == 63) wsum[w] = inc;
    __syncthreads();
    int wo = 0;
    for (int k = 0; k < w; ++k) wo += wsum[k];
    if (tid < NB) bsum[tid] = wo + inc - v;
    if (tid == 0) rowptr[NN] = E;
}

// ---------------- finish ---------------------------------------------------------
__global__ void k_finish(int* __restrict__ rowptr, const int* __restrict__ bsum,
                         const int* __restrict__ deg, int* __restrict__ cursor,
                         float* __restrict__ deg_inv) {
    int i = blockIdx.x * 256 + threadIdx.x;
    if (i < NN) {
        int rp = rowptr[i] + bsum[i >> 8];
        rowptr[i] = rp;
        cursor[i] = rp;
        deg_inv[i] = 1.0f / fmaxf((float)deg[i], 1.0f);
    }
}

// ---------------- gather1: h = mean(bf16 y1[nbrs])*deg_inv + xr + b1l; BN stats --
__global__ __launch_bounds__(256) void k_gather1(const unsigned short* __restrict__ y1,
        const int* __restrict__ rowptr, const int* __restrict__ eidx,
        const float* __restrict__ b1l,
        const float* __restrict__ deg_inv, float* __restrict__ h,
        float* __restrict__ stats) {
    const int tid = threadIdx.x;
    const int f = tid & 63, w = tid >> 6;
    const float bias = b1l[f];
    float a1 = 0.f, a2 = 0.f;
    for (int n = blockIdx.x * 4 + w; n < NN; n += gridDim.x * 4) {
        int beg = rowptr[n], end = rowptr[n + 1];
        float s0 = 0.f, s1 = 0.f, s2 = 0.f, s3 = 0.f;
        int j = beg;
        for (; j + 3 < end; j += 4) {
            int i0 = eidx[j], i1 = eidx[j + 1], i2 = eidx[j + 2], i3 = eidx[j + 3];
            s0 += bf2f(y1[(size_t)i0 * 64 + f]);
            s1 += bf2f(y1[(size_t)i1 * 64 + f]);
            s2 += bf2f(y1[(size_t)i2 * 64 + f]);
            s3 += bf2f(y1[(size_t)i3 * 64 + f]);
        }
        for (; j < end; ++j) s0 += bf2f(y1[(size_t)eidx[j] * 64 + f]);
        size_t off = (size_t)n * 64 + f;
        float hv = fmaf((s0 + s1) + (s2 + s3), deg_inv[n], h[off] + bias); // h holds xr
        h[off] = hv;
        a1 += hv; a2 = fmaf(hv, hv, a2);
    }
    __shared__ float sA[4][64], sB[4][64];
    sA[w][f] = a1; sB[w][f] = a2;
    __syncthreads();
    if (w == 0) {
        atomicAdd(&stats[f],      sA[0][f] + sA[1][f] + sA[2][f] + sA[3][f]);
        atomicAdd(&stats[64 + f], sB[0][f] + sB[1][f] + sB[2][f] + sB[3][f]);
    }
}

// ---------------- GEMM2 (BN finalize + BN+ReLU fused): y2(bf16), hr2(fp32) -------
__global__ __launch_bounds__(256) void k_gemm2(const float* __restrict__ h,
        const float* __restrict__ W2l, const float* __restrict__ W2r,
        const float* __restrict__ stats, const float* __restrict__ gamma,
        const float* __restrict__ beta,
        unsigned short* __restrict__ y2, float* __restrict__ hr2) {
    __shared__ float lh[64][68];
    __shared__ float lw[64][36];
    __shared__ float lsc[64], lsh[64];
    const int tid = threadIdx.x;
    if (tid < 64) {   // BN finalize (redundant per block, cheap)
        float mu = stats[tid] * (1.0f / NN);
        float var = stats[64 + tid] * (1.0f / NN) - mu * mu;
        float sc = gamma[tid] * rsqrtf(var + 1e-5f);
        lsc[tid] = sc;
        lsh[tid] = beta[tid] - mu * sc;
    }
    for (int idx = tid; idx < 32 * 64; idx += 256) {
        int j = idx >> 6, k = idx & 63;
        lw[k][j] = (j < 16) ? W2l[idx] : W2r[idx - 1024];
    }
    __syncthreads();
    const int row0 = blockIdx.x * 64;
    for (int i = 0; i < 4; ++i) {
        int f4 = i * 256 + tid;
        int r = f4 >> 4;
        int k4 = (f4 & 15) << 2;
        int grow = row0 + r;
        float4 v = make_float4(0.f, 0.f, 0.f, 0.f);
        if (grow < NN) v = *(const float4*)(h + (size_t)grow * 64 + k4);
        float4 sc = *(const float4*)(&lsc[k4]);
        float4 sh = *(const float4*)(&lsh[k4]);
        float4 o;
        o.x = fmaxf(fmaf(v.x, sc.x, sh.x), 0.f);
        o.y = fmaxf(fmaf(v.y, sc.y, sh.y), 0.f);
        o.z = fmaxf(fmaf(v.z, sc.z, sh.z), 0.f);
        o.w = fmaxf(fmaf(v.w, sc.w, sh.w), 0.f);
        *(float4*)(&lh[r][k4]) = o;
    }
    __syncthreads();
    const int cg = tid & 7;
    const int rl = tid >> 3;
    #pragma unroll
    for (int p = 0; p < 2; ++p) {
        int r = p * 32 + rl;
        int grow = row0 + r;
        float ax = 0.f, ay = 0.f, az = 0.f, aw = 0.f;
        #pragma unroll
        for (int k = 0; k < 64; ++k) {
            float hv = lh[r][k];
            float4 wv = *(const float4*)(&lw[k][cg << 2]);
            ax = fmaf(hv, wv.x, ax); ay = fmaf(hv, wv.y, ay);
            az = fmaf(hv, wv.z, az); aw = fmaf(hv, wv.w, aw);
        }
        if (grow < NN) {
            int c = cg << 2;
            if (c < 16) {
                ushort4 o;
                o.x = f2bf(ax); o.y = f2bf(ay); o.z = f2bf(az); o.w = f2bf(aw);
                *(ushort4*)(y2 + (size_t)grow * 16 + c) = o;
            } else {
                *(float4*)(hr2 + (size_t)grow * 16 + (c - 16)) = make_float4(ax, ay, az, aw);
            }
        }
    }
}

// ---------------- gather2 + epilogue: emb + logits straight to d_out -------------
__global__ __launch_bounds__(256) void k_gather2(const unsigned short* __restrict__ y2,
        const int* __restrict__ rowptr, const int* __restrict__ eidx,
        const float* __restrict__ hr2, const float* __restrict__ b2l,
        const float* __restrict__ deg_inv, const float* __restrict__ Wc,
        const float* __restrict__ bc, float* __restrict__ out) {
    const int tid = threadIdx.x;
    const int f = tid & 15, g = tid >> 4;
    const float wc0 = Wc[f], wc1 = Wc[16 + f];
    const float bias = b2l[f];
    for (int n = blockIdx.x * 16 + g; n < NN; n += gridDim.x * 16) {
        int beg = rowptr[n], end = rowptr[n + 1];
        float s0 = 0.f, s1 = 0.f, s2 = 0.f, s3 = 0.f;
        int j = beg;
        for (; j + 3 < end; j += 4) {
            int i0 = eidx[j], i1 = eidx[j + 1], i2 = eidx[j + 2], i3 = eidx[j + 3];
            s0 += bf2f(y2[(size_t)i0 * 16 + f]);
            s1 += bf2f(y2[(size_t)i1 * 16 + f]);
            s2 += bf2f(y2[(size_t)i2 * 16 + f]);
            s3 += bf2f(y2[(size_t)i3 * 16 + f]);
        }
        for (; j < end; ++j) s0 += bf2f(y2[(size_t)eidx[j] * 16 + f]);
        float e = fmaf((s0 + s1) + (s2 + s3), deg_inv[n], hr2[(size_t)n * 16 + f] + bias);
        out[(size_t)(2 * NN) + (size_t)n * 16 + f] = e;
        float l0 = e * wc0, l1 = e * wc1;
        #pragma unroll
        for (int m = 1; m < 16; m <<= 1) {
            l0 += __shfl_xor(l0, m, 64);
            l1 += __shfl_xor(l1, m, 64);
        }
        if (f == 0) {
            out[(size_t)n * 2]     = l0 + bc[0];
            out[(size_t)n * 2 + 1] = l1 + bc[1];
        }
    }
}

extern "C" void kernel_launch(void* const* d_in, const int* in_sizes, int n_in,
                              void* d_out, int out_size, void* d_ws, size_t ws_size,
                              hipStream_t stream) {
    const float* x     = (const float*)d_in[0];
    const int*   src   = (const int*)d_in[1];
    const int*   dst   = (const int*)d_in[2];
    const float* W1l   = (const float*)d_in[3];
    const float* b1l   = (const float*)d_in[4];
    const float* W1r   = (const float*)d_in[5];
    const float* gamma = (const float*)d_in[6];
    const float* beta  = (const float*)d_in[7];
    const float* W2l   = (const float*)d_in[8];
    const float* b2l   = (const float*)d_in[9];
    const float* W2r   = (const float*)d_in[10];
    const float* Wc    = (const float*)d_in[11];
    const float* bc    = (const float*)d_in[12];
    const int E = in_sizes[1];

    // ---- workspace layout (floats) ----------------------------------------------
    // rowptr[100352] | deg_inv[100352] | stats[256] | deg_i[100352] | cursor[100352]
    // | eidx[E] | y1 region[NN*64 fl] (bf16 y1 uses half) | h[NN*64]
    // overlays: bsum in eidx region; y2(bf16)/hr2 reuse y1 region after gather1;
    //           xr IS h (fused gemm writes it, gather1 updates in place).
    float* ws      = (float*)d_ws;
    int*   rowptr  = (int*)ws;
    float* deg_inv = ws + 100352;
    float* stats   = ws + 200704;
    int*   deg_i   = (int*)(ws + 200960);
    int*   cursor  = (int*)(ws + 301312);
    int*   eidx    = (int*)(ws + 401664);
    float* y1reg   = ws + 401664 + (size_t)E;
    float* h       = y1reg + (size_t)NN * 64;
    unsigned short* y1 = (unsigned short*)y1reg;
    int*   bsum    = eidx;
    unsigned short* y2 = (unsigned short*)y1reg;
    float* hr2     = y1reg + (size_t)NN * 8;   // after y2's NN*16 ushorts
    float* out     = (float*)d_out;

    hipMemsetAsync(deg_i, 0, NN * sizeof(int), stream);
    hipMemsetAsync(stats, 0, 256 * sizeof(float), stream);

    // fusedA: deg + dual-GEMM tiles [0,782). 98 groups x 16 blocks.
    k_fusedA<<<1568, 256, 0, stream>>>(x, W1l, W1r, dst, deg_i, y1, h, E);

    k_scanA<<<NB, 256, 0, stream>>>(deg_i, rowptr, bsum);
    k_scanB<<<1, 512, 0, stream>>>(bsum, rowptr, E);
    k_finish<<<NB, 256, 0, stream>>>(rowptr, bsum, deg_i, cursor, deg_inv);

    // fusedB: plain fill (v<4) + dual-GEMM tiles [782,1563) (v>=4).
    k_fusedB<<<1568, 256, 0, stream>>>(x, W1l, W1r, src, dst, cursor, eidx, y1, h, E);

    k_gather1<<<4096, 256, 0, stream>>>(y1, rowptr, eidx, b1l, deg_inv, h, stats);

    k_gemm2<<<(NN + 63) / 64, 256, 0, stream>>>(h, W2l, W2r, stats, gamma, beta, y2, hr2);

    k_gather2<<<2048, 256, 0, stream>>>(y2, rowptr, eidx, hr2, b2l, deg_inv, Wc, bc, out);
}